// Round 10
// baseline (769.213 us; speedup 1.0000x reference)
//
#include <hip/hip_runtime.h>

// VectorQuantizer on MI355X. d_out = FLOAT32 concat:
// [0]=vq_loss, [1]=commitment, [2..2+B)=idx(float), [2+B..)=quantized (B x 256).
// Round 10: kill the binning permutation. Waves own 32 CONSECUTIVE rows; loop
// over the 4 codebook quadrants, masked top-2 keep (row's own group only).
// All z reads / idx writes / quantized writes are sequential streams.
// 4x MFMA (util 5->20%) buys streaming BW. Epilogue = R7 verbatim + R9's
// fp64-norm THETA=0.002 gate. Kernels: prep3 | score9 | fin.

#define B_ROWS   131072
#define D_EMB    256
#define TPB      256
#define SGRID    1024                 // 1024 blocks x 4 waves x 32 rows = 131072
#define THETA    0.002f

// ---- workspace layout (bytes) ----
#define WS_WSUM   0                        // 64 doubles (512B)
#define WS_CBH    1024                     // 512*256 bf16 hi (262144B)
#define WS_CBL    (WS_CBH + 262144)        // bf16 lo
#define WS_EN     (WS_CBL + 262144)        // 512 f32 norms
#define WS_NEED   (WS_EN + 2048)
#define WS_FLAGS  8

typedef __attribute__((ext_vector_type(8))) short bf16x8;
typedef __attribute__((ext_vector_type(4))) float f32x4;

__device__ __forceinline__ float bf2f(unsigned short u) {
    return __uint_as_float(((unsigned)u) << 16);
}

__device__ __forceinline__ void splitA(const float4& a0, const float4& a1,
                                       bf16x8& ah, bf16x8& al) {
    float ff[8] = {a0.x, a0.y, a0.z, a0.w, a1.x, a1.y, a1.z, a1.w};
    #pragma unroll
    for (int j = 0; j < 8; ++j) {
        unsigned u = __float_as_uint(ff[j]);
        ah[j] = (short)(u >> 16);
        float r = ff[j] - __uint_as_float(u & 0xffff0000u);
        al[j] = (short)(__float_as_uint(r) >> 16);
    }
}

// ============ K1: split codebook + fp64 norms ============
__global__ void vq_prep3(const float* __restrict__ cbf,
                         unsigned short* __restrict__ cbh,
                         unsigned short* __restrict__ cbl,
                         float* __restrict__ eN) {
    const int code = blockIdx.x;     // 512
    const int lane = threadIdx.x;    // 64
    float4 v = *(const float4*)(cbf + code * 256 + lane * 4);
    unsigned u0 = __float_as_uint(v.x), u1 = __float_as_uint(v.y);
    unsigned u2 = __float_as_uint(v.z), u3 = __float_as_uint(v.w);
    ushort4 h = make_ushort4((unsigned short)(u0 >> 16), (unsigned short)(u1 >> 16),
                             (unsigned short)(u2 >> 16), (unsigned short)(u3 >> 16));
    float r0 = v.x - __uint_as_float(u0 & 0xffff0000u);
    float r1 = v.y - __uint_as_float(u1 & 0xffff0000u);
    float r2 = v.z - __uint_as_float(u2 & 0xffff0000u);
    float r3 = v.w - __uint_as_float(u3 & 0xffff0000u);
    ushort4 l = make_ushort4((unsigned short)(__float_as_uint(r0) >> 16),
                             (unsigned short)(__float_as_uint(r1) >> 16),
                             (unsigned short)(__float_as_uint(r2) >> 16),
                             (unsigned short)(__float_as_uint(r3) >> 16));
    *(ushort4*)(cbh + code * 256 + lane * 4) = h;
    *(ushort4*)(cbl + code * 256 + lane * 4) = l;
    double s = fma((double)v.x, (double)v.x,
               fma((double)v.y, (double)v.y,
               fma((double)v.z, (double)v.z, (double)v.w * (double)v.w)));
    #pragma unroll
    for (int d = 1; d < 64; d <<= 1) s += __shfl_xor(s, d);
    if (lane == 0) eN[code] = (float)s;
}

// ============ K2: scoring, 32 consecutive rows per wave, 4 quadrant passes ============
__global__ __launch_bounds__(TPB, 3) void vq_score9(
    const int* __restrict__ nt,
    const float* __restrict__ zf,
    const float* __restrict__ cbf,
    const unsigned short* __restrict__ cbh,
    const unsigned short* __restrict__ cbl,
    const float* __restrict__ eN,
    float* __restrict__ out,
    double* __restrict__ wsum)
{
    __shared__ int2   sT[4][2][16];
    __shared__ float2 sM[4][2][16];
    __shared__ float  sZZ[4][16];
    __shared__ int    sW[4][32];
    __shared__ int    sG[4][32];
    __shared__ double sRed[4];
    __shared__ int    sI64;

    const int tid  = threadIdx.x;
    const int wave = tid >> 6;
    const int lane = tid & 63;
    const int col  = lane & 15;
    const int quad = lane >> 4;

    if (tid >= 64 && tid < 128) {        // wave 1: block-local i64 detect
        int o = (nt[2 * (tid - 64) + 1] != 0) ? 1 : 0;
        unsigned long long m = __ballot(o != 0);
        if (tid == 64) sI64 = (m == 0ULL) ? 1 : 0;
    }
    __syncthreads();
    const int i64   = sI64;
    const int wbase = (blockIdx.x * 4 + wave) * 32;

    if (lane < 32) {                     // per-wave group table (consecutive nt read)
        int tv = i64 ? nt[2 * (wbase + lane)] : nt[wbase + lane];
        sG[wave][lane] = (tv == 5) ? 0 : (tv == 6) ? 1 : (tv == 7) ? 2 : 3;
    }

    const float* za0 = zf + (wbase + col) * 256 + quad * 8;
    const float* za1 = zf + (wbase + 16 + col) * 256 + quad * 8;

    double zz0 = 0.0, zz1 = 0.0;
    double lacc = 0.0;

    for (int gc = 0; gc < 4; ++gc) {
        const unsigned short* bhp = cbh + (gc * 128 + col) * 256 + quad * 8;
        const unsigned short* blp = cbl + (gc * 128 + col) * 256 + quad * 8;

        f32x4 acc[2][8];
        #pragma unroll
        for (int st = 0; st < 2; ++st)
            #pragma unroll
            for (int t = 0; t < 8; ++t) acc[st][t] = (f32x4){0.f, 0.f, 0.f, 0.f};

        #pragma unroll
        for (int c = 0; c < 8; ++c) {
            float4 a00 = *(const float4*)(za0 + c * 32);
            float4 a01 = *(const float4*)(za0 + c * 32 + 4);
            float4 a10 = *(const float4*)(za1 + c * 32);
            float4 a11 = *(const float4*)(za1 + c * 32 + 4);
            if (gc == 0) {
                zz0 = fma((double)a00.x, (double)a00.x, fma((double)a00.y, (double)a00.y,
                      fma((double)a00.z, (double)a00.z, fma((double)a00.w, (double)a00.w, zz0))));
                zz0 = fma((double)a01.x, (double)a01.x, fma((double)a01.y, (double)a01.y,
                      fma((double)a01.z, (double)a01.z, fma((double)a01.w, (double)a01.w, zz0))));
                zz1 = fma((double)a10.x, (double)a10.x, fma((double)a10.y, (double)a10.y,
                      fma((double)a10.z, (double)a10.z, fma((double)a10.w, (double)a10.w, zz1))));
                zz1 = fma((double)a11.x, (double)a11.x, fma((double)a11.y, (double)a11.y,
                      fma((double)a11.z, (double)a11.z, fma((double)a11.w, (double)a11.w, zz1))));
            }
            bf16x8 ah0, al0, ah1, al1;
            splitA(a00, a01, ah0, al0);
            splitA(a10, a11, ah1, al1);
            #pragma unroll
            for (int t = 0; t < 8; ++t) {
                bf16x8 bh = *(const bf16x8*)(bhp + t * 4096 + c * 32);
                bf16x8 bl = *(const bf16x8*)(blp + t * 4096 + c * 32);
                acc[0][t] = __builtin_amdgcn_mfma_f32_16x16x32_bf16(ah0, bh, acc[0][t], 0, 0, 0);
                acc[0][t] = __builtin_amdgcn_mfma_f32_16x16x32_bf16(al0, bh, acc[0][t], 0, 0, 0);
                acc[0][t] = __builtin_amdgcn_mfma_f32_16x16x32_bf16(ah0, bl, acc[0][t], 0, 0, 0);
                acc[1][t] = __builtin_amdgcn_mfma_f32_16x16x32_bf16(ah1, bh, acc[1][t], 0, 0, 0);
                acc[1][t] = __builtin_amdgcn_mfma_f32_16x16x32_bf16(al1, bh, acc[1][t], 0, 0, 0);
                acc[1][t] = __builtin_amdgcn_mfma_f32_16x16x32_bf16(ah1, bl, acc[1][t], 0, 0, 0);
            }
        }

        float e8[8];
        #pragma unroll
        for (int t = 0; t < 8; ++t) e8[t] = eN[gc * 128 + t * 16 + col];

        // ---- per-row top-2 of this quadrant; keep only rows whose group == gc ----
        #pragma unroll
        for (int st = 0; st < 2; ++st) {
            #pragma unroll
            for (int r = 0; r < 4; ++r) {
                float m1 = __builtin_inff(), m2 = __builtin_inff();
                int   i1 = 0x7fffffff,      i2 = 0x7fffffff;
                #pragma unroll
                for (int t = 0; t < 8; ++t) {
                    float sc = e8[t] - 2.f * acc[st][t][r];
                    int   ci = gc * 128 + t * 16 + col;
                    if (sc < m1 || (sc == m1 && ci < i1)) { m2 = m1; i2 = i1; m1 = sc; i1 = ci; }
                    else if (sc < m2 || (sc == m2 && ci < i2)) { m2 = sc; i2 = ci; }
                }
                #pragma unroll
                for (int d2 = 1; d2 < 16; d2 <<= 1) {
                    float b1 = __shfl_xor(m1, d2);
                    int  bi1 = __shfl_xor(i1, d2);
                    float b2 = __shfl_xor(m2, d2);
                    int  bi2 = __shfl_xor(i2, d2);
                    if (b1 < m1 || (b1 == m1 && bi1 < i1)) {
                        float om = m1; int oi = i1;
                        m1 = b1; i1 = bi1;
                        if (b2 < om || (b2 == om && bi2 < oi)) { m2 = b2; i2 = bi2; }
                        else                                   { m2 = om; i2 = oi; }
                    } else {
                        if (b1 < m2 || (b1 == m2 && bi1 < i2)) { m2 = b1; i2 = bi1; }
                    }
                }
                if (col == 0) {
                    const int row = quad * 4 + r;
                    if (sG[wave][st * 16 + row] == gc) {
                        sT[wave][st][row] = make_int2(i1, i2);
                        sM[wave][st][row] = make_float2(m1, m2);
                    }
                }
            }
        }
    }
    zz0 += __shfl_xor(zz0, 16); zz0 += __shfl_xor(zz0, 32);
    zz1 += __shfl_xor(zz1, 16); zz1 += __shfl_xor(zz1, 32);

    // ---- epilogue per subtile (all rows valid; grow consecutive) ----
    for (int st = 0; st < 2; ++st) {
        if (quad == 0) sZZ[wave][col] = (float)(st ? zz1 : zz0);

        const int s  = lane >> 2;
        const int pq = lane & 3;
        const int grow = wbase + st * 16 + s;
        int2   tt = sT[wave][st][s];
        float2 mm = sM[wave][st][s];
        float zzr = sZZ[wave][s];
        int c1 = tt.x, c2 = tt.y;
        float scm1 = mm.x, scm2 = mm.y;

        int    wfin  = c1;
        double dfull = (double)(zzr + scm1);
        const bool need = (scm2 - scm1 <= THETA);

        if (__any(need)) {            // rare: fp64 refine of close top-2
            double d1c = 0.0, d2c = 0.0;
            if (need) {
                const float* zp = zf  + grow * 256 + pq * 64;
                const float* p1 = cbf + c1 * 256 + pq * 64;
                const float* p2 = cbf + c2 * 256 + pq * 64;
                #pragma unroll 4
                for (int it = 0; it < 16; ++it) {
                    float4 fz = *(const float4*)(zp + it * 4);
                    float4 g1 = *(const float4*)(p1 + it * 4);
                    float4 g2 = *(const float4*)(p2 + it * 4);
                    double e;
                    e = (double)fz.x - (double)g1.x; d1c = fma(e, e, d1c);
                    e = (double)fz.y - (double)g1.y; d1c = fma(e, e, d1c);
                    e = (double)fz.z - (double)g1.z; d1c = fma(e, e, d1c);
                    e = (double)fz.w - (double)g1.w; d1c = fma(e, e, d1c);
                    e = (double)fz.x - (double)g2.x; d2c = fma(e, e, d2c);
                    e = (double)fz.y - (double)g2.y; d2c = fma(e, e, d2c);
                    e = (double)fz.z - (double)g2.z; d2c = fma(e, e, d2c);
                    e = (double)fz.w - (double)g2.w; d2c = fma(e, e, d2c);
                }
            }
            double t1 = d1c + __shfl_xor(d1c, 1); t1 += __shfl_xor(t1, 2);
            double t2 = d2c + __shfl_xor(d2c, 1); t2 += __shfl_xor(t2, 2);
            if (need) {
                bool take1 = (t1 < t2) || (t1 == t2 && c1 < c2);
                wfin  = take1 ? c1 : c2;
                dfull = take1 ? t1 : t2;
            }
        }

        if (pq == 0) {
            lacc += dfull;
            sW[wave][st * 16 + s] = wfin;
            out[2 + grow] = (float)wfin;       // consecutive 4B stores
        }
    }

    // ---- wave-cooperative coalesced winner copy (sequential output rows) ----
    for (int r = 0; r < 32; ++r) {
        const int wv = sW[wave][r];
        const float4 v = *(const float4*)(cbf + wv * 256 + lane * 4);   // 16B aligned
        const int ob = 2 + B_ROWS + (wbase + r) * 256;                  // == 2 mod 4
        *(float2*)(out + ob + lane * 4)     = make_float2(v.x, v.y);
        *(float2*)(out + ob + lane * 4 + 2) = make_float2(v.z, v.w);
    }

    #pragma unroll
    for (int d2 = 1; d2 < 64; d2 <<= 1) lacc += __shfl_xor(lacc, d2);
    if (lane == 0) sRed[wave] = lacc;
    __syncthreads();
    if (tid == 0) atomicAdd(&wsum[blockIdx.x & 63], sRed[0] + sRed[1] + sRed[2] + sRed[3]);
}

// ===================== tiny-ws fallback (fp32 VALU path) =====================
__global__ void vq_detect(const unsigned short* cb, const int* nt, int* flag) {
    __shared__ int cnt, odd;
    if (threadIdx.x == 0) { cnt = 0; odd = 0; }
    __syncthreads();
    int c = 0, o = 0;
    for (int i = threadIdx.x; i < 512; i += 64) {
        unsigned short u = cb[2 * i];
        int e = (u >> 7) & 0xFF;
        if (e < 100 || e > 140) c++;
    }
    if (nt[2 * threadIdx.x + 1] != 0) o = 1;
    atomicAdd(&cnt, c);
    atomicAdd(&odd, o);
    __syncthreads();
    if (threadIdx.x == 0) {
        flag[0] = (cnt < 50) ? 1 : 0;
        flag[1] = (odd == 0) ? 1 : 0;
    }
}

__global__ __launch_bounds__(512, 2) void vq_main_f32(
    const int* __restrict__ nt,
    const float* __restrict__ zff,
    const float* __restrict__ cbf,
    float* __restrict__ out,
    double* __restrict__ wsum,
    const int* __restrict__ flag)
{
    if (flag[0] != 0) return;
    const int i64 = flag[1];

    __shared__ float  sE[256 * 132];
    __shared__ float  sZ[128 * 32];
    __shared__ int    sList[512];
    __shared__ int    sCnt[4], sPos[4];
    __shared__ int    sTop1[128], sTop2[128];
    __shared__ float  sEe[128];
    __shared__ double sRed[8];

    const int tid  = threadIdx.x;
    const int row0 = blockIdx.x * 512;

    if (tid < 4) { sCnt[tid] = 0; sPos[tid] = 0; }
    __syncthreads();
    {
        int t = i64 ? nt[2 * (row0 + tid)] : nt[row0 + tid];
        int g = (t == 5) ? 0 : (t == 6) ? 1 : (t == 7) ? 2 : 3;
        atomicAdd(&sCnt[g], 1);
        __syncthreads();
        int o1 = sCnt[0], o2 = o1 + sCnt[1], o3 = o2 + sCnt[2];
        int offg = (g == 0) ? 0 : (g == 1) ? o1 : (g == 2) ? o2 : o3;
        int p = atomicAdd(&sPos[g], 1);
        sList[offg + p] = row0 + tid;
    }
    __syncthreads();

    int cnt[4], off[4];
    cnt[0] = sCnt[0]; cnt[1] = sCnt[1]; cnt[2] = sCnt[2]; cnt[3] = sCnt[3];
    off[0] = 0; off[1] = cnt[0]; off[2] = off[1] + cnt[1]; off[3] = off[2] + cnt[2];

    const int ccol = tid & 31, rrow = tid >> 5;
    const int c0 = ccol * 4, rbase = rrow * 8;
    double lacc = 0.0;

    for (int gg = 0; gg < 4; ++gg) {
        const int n = cnt[gg];
        if (n == 0) continue;
        __syncthreads();
        for (int i = tid; i < 128 * 256; i += 512) {
            int c = i >> 8, k = i & 255;
            sE[k * 132 + c] = cbf[(gg * 128 + c) * 256 + k];
        }
        __syncthreads();
        if (tid < 128) {
            float s = 0.f;
            for (int k = 0; k < 256; ++k) { float v = sE[k * 132 + tid]; s = fmaf(v, v, s); }
            sEe[tid] = s;
        }
        __syncthreads();

        const int ntiles = (n + 127) >> 7;
        for (int tI = 0; tI < ntiles; ++tI) {
            const int tbase = off[gg] + tI * 128;
            const int nrows = min(128, n - tI * 128);
            float acc[8][4];
            #pragma unroll
            for (int r = 0; r < 8; ++r)
                #pragma unroll
                for (int q = 0; q < 4; ++q) acc[r][q] = 0.f;

            for (int kb = 0; kb < 8; ++kb) {
                __syncthreads();
                #pragma unroll
                for (int it = 0; it < 2; ++it) {
                    int i = it * 512 + tid;
                    int s = i >> 3, j = i & 7;
                    float4 v = make_float4(0.f, 0.f, 0.f, 0.f);
                    if (s < nrows) {
                        int gr = sList[tbase + s];
                        v = *(const float4*)(zff + gr * 256 + kb * 32 + j * 4);
                    }
                    *(float4*)&sZ[s * 32 + j * 4] = v;
                }
                __syncthreads();
                #pragma unroll
                for (int k4 = 0; k4 < 8; ++k4) {
                    const int kk = kb * 32 + k4 * 4;
                    const float4 e0 = *(const float4*)&sE[(kk + 0) * 132 + c0];
                    const float4 e1 = *(const float4*)&sE[(kk + 1) * 132 + c0];
                    const float4 e2 = *(const float4*)&sE[(kk + 2) * 132 + c0];
                    const float4 e3 = *(const float4*)&sE[(kk + 3) * 132 + c0];
                    #pragma unroll
                    for (int r = 0; r < 8; ++r) {
                        const float4 zv = *(const float4*)&sZ[(rbase + r) * 32 + k4 * 4];
                        acc[r][0] = fmaf(zv.x, e0.x, fmaf(zv.y, e1.x, fmaf(zv.z, e2.x, fmaf(zv.w, e3.x, acc[r][0]))));
                        acc[r][1] = fmaf(zv.x, e0.y, fmaf(zv.y, e1.y, fmaf(zv.z, e2.y, fmaf(zv.w, e3.y, acc[r][1]))));
                        acc[r][2] = fmaf(zv.x, e0.z, fmaf(zv.y, e1.z, fmaf(zv.z, e2.z, fmaf(zv.w, e3.z, acc[r][2]))));
                        acc[r][3] = fmaf(zv.x, e0.w, fmaf(zv.y, e1.w, fmaf(zv.z, e2.w, fmaf(zv.w, e3.w, acc[r][3]))));
                    }
                }
            }

            float eq[4] = { sEe[c0], sEe[c0 + 1], sEe[c0 + 2], sEe[c0 + 3] };
            for (int r = 0; r < 8; ++r) {
                float m1 = __builtin_inff(), m2 = __builtin_inff();
                int   i1 = 0x7fffffff,      i2 = 0x7fffffff;
                #pragma unroll
                for (int q = 0; q < 4; ++q) {
                    float sc = eq[q] - 2.f * acc[r][q];
                    int   ci = c0 + q;
                    if (sc < m1 || (sc == m1 && ci < i1)) { m2 = m1; i2 = i1; m1 = sc; i1 = ci; }
                    else if (sc < m2 || (sc == m2 && ci < i2)) { m2 = sc; i2 = ci; }
                }
                #pragma unroll
                for (int d = 1; d < 32; d <<= 1) {
                    float b1 = __shfl_xor(m1, d);
                    int  bi1 = __shfl_xor(i1, d);
                    float b2 = __shfl_xor(m2, d);
                    int  bi2 = __shfl_xor(i2, d);
                    if (b1 < m1 || (b1 == m1 && bi1 < i1)) {
                        float om = m1; int oi = i1;
                        m1 = b1; i1 = bi1;
                        if (b2 < om || (b2 == om && bi2 < oi)) { m2 = b2; i2 = bi2; }
                        else                                   { m2 = om; i2 = oi; }
                    } else {
                        if (b1 < m2 || (b1 == m2 && bi1 < i2)) { m2 = b1; i2 = bi1; }
                    }
                }
                if (ccol == 0) { sTop1[rbase + r] = i1; sTop2[rbase + r] = i2; }
            }
            __syncthreads();

            {
                const int s  = tid >> 2;
                const int pq = tid & 3;
                const bool valid = (s < nrows);
                double d1c = 0.0, d2c = 0.0;
                int gr = 0, c1g = 0, c2g = 0;
                if (valid) {
                    gr  = sList[tbase + s];
                    c1g = gg * 128 + sTop1[s];
                    c2g = gg * 128 + sTop2[s];
                    #pragma unroll 4
                    for (int it = 0; it < 16; ++it) {
                        float4 fz = *(const float4*)(zff + gr  * 256 + pq * 64 + it * 4);
                        float4 f1 = *(const float4*)(cbf + c1g * 256 + pq * 64 + it * 4);
                        float4 f2 = *(const float4*)(cbf + c2g * 256 + pq * 64 + it * 4);
                        double e;
                        e = (double)fz.x - (double)f1.x; d1c = fma(e, e, d1c);
                        e = (double)fz.y - (double)f1.y; d1c = fma(e, e, d1c);
                        e = (double)fz.z - (double)f1.z; d1c = fma(e, e, d1c);
                        e = (double)fz.w - (double)f1.w; d1c = fma(e, e, d1c);
                        e = (double)fz.x - (double)f2.x; d2c = fma(e, e, d2c);
                        e = (double)fz.y - (double)f2.y; d2c = fma(e, e, d2c);
                        e = (double)fz.z - (double)f2.z; d2c = fma(e, e, d2c);
                        e = (double)fz.w - (double)f2.w; d2c = fma(e, e, d2c);
                    }
                }
                double t1 = d1c + __shfl_xor(d1c, 1); t1 += __shfl_xor(t1, 2);
                double t2 = d2c + __shfl_xor(d2c, 1); t2 += __shfl_xor(t2, 2);
                if (valid) {
                    bool take1 = (t1 < t2) || (t1 == t2 && c1g < c2g);
                    int  w = take1 ? c1g : c2g;
                    lacc += take1 ? d1c : d2c;
                    const int obase = 2 + B_ROWS + gr * 256 + pq * 64;
                    #pragma unroll 4
                    for (int it = 0; it < 16; ++it) {
                        float4 f4 = *(const float4*)(cbf + w * 256 + pq * 64 + it * 4);
                        *(float2*)(out + obase + it * 4)     = make_float2(f4.x, f4.y);
                        *(float2*)(out + obase + it * 4 + 2) = make_float2(f4.z, f4.w);
                    }
                    if (pq == 0) out[2 + gr] = (float)w;
                }
            }
        }
    }

    #pragma unroll
    for (int d = 1; d < 64; d <<= 1) lacc += __shfl_xor(lacc, d);
    if ((tid & 63) == 0) sRed[tid >> 6] = lacc;
    __syncthreads();
    if (tid == 0) {
        double s = 0.0;
        #pragma unroll
        for (int i = 0; i < 8; ++i) s += sRed[i];
        atomicAdd(wsum, s);
    }
}

__global__ void vq_fin(const double* wsum, float* out, int n) {
    if (threadIdx.x == 0 && blockIdx.x == 0) {
        double m = 0.0;
        for (int i = 0; i < n; ++i) m += wsum[i];
        m /= ((double)B_ROWS * (double)D_EMB);
        out[0] = (float)m;
        out[1] = (float)(0.25 * m);
    }
}

extern "C" void kernel_launch(void* const* d_in, const int* in_sizes, int n_in,
                              void* d_out, int out_size, void* d_ws, size_t ws_size,
                              hipStream_t stream) {
    const int*   nt  = (const int*)d_in[0];
    const float* zf  = (const float*)d_in[1];
    const float* cbf = (const float*)d_in[2];
    float*  out  = (float*)d_out;
    double* wsum = (double*)((char*)d_ws + WS_WSUM);

    hipMemsetAsync(d_ws, 0, 1024, stream);

    if (ws_size >= (size_t)WS_NEED) {
        unsigned short* cbh = (unsigned short*)((char*)d_ws + WS_CBH);
        unsigned short* cbl = (unsigned short*)((char*)d_ws + WS_CBL);
        float* eN = (float*)((char*)d_ws + WS_EN);
        vq_prep3<<<512, 64, 0, stream>>>(cbf, cbh, cbl, eN);
        vq_score9<<<SGRID, TPB, 0, stream>>>(nt, zf, cbf, cbh, cbl, eN, out, wsum);
        vq_fin<<<1, 64, 0, stream>>>(wsum, out, 64);
    } else {
        int* flag = (int*)((char*)d_ws + WS_FLAGS);
        vq_detect<<<1, 64, 0, stream>>>((const unsigned short*)cbf, nt, flag);
        vq_main_f32<<<256, 512, 0, stream>>>(nt, zf, cbf, out, wsum, flag);
        vq_fin<<<1, 64, 0, stream>>>(wsum, out, 1);
    }
}

// Round 11
// 567.189 us; speedup vs baseline: 1.3562x; 1.3562x over previous
//
#include <hip/hip_runtime.h>

// VectorQuantizer on MI355X. d_out = FLOAT32 concat:
// [0]=vq_loss, [1]=commitment, [2..2+B)=idx(float), [2+B..)=quantized (B x 256).
// Round 11: R7 (best verified) with K-loop split into two 16-row passes:
// acc[2][8]->acc[8] per pass (64->32 AGPRs), B re-read from L2 (free), A/z
// traffic unchanged. Total regs <=128 -> __launch_bounds__(256,4) doubles
// resident waves/SIMD. Everything else R7 verbatim.

#define B_ROWS   131072
#define D_EMB    256
#define TPB      256
#define SGRID    1025                 // 1025 blocks x 4 waves >= max 4100 tiles
#define THETA    0.0625f

// ---- workspace layout (bytes) ----
#define WS_WSUM   0                        // 64 doubles (512B)
#define WS_GCNT   516                      // 4 ints
#define WS_GPOSD  532                      // 4 ints (scatter cursors)
#define WS_CBH    1024                     // 512*256 bf16 hi (262144B)
#define WS_CBL    (WS_CBH + 262144)        // bf16 lo
#define WS_EN     (WS_CBL + 262144)        // 512 f32 norms
#define WS_ROWS   (WS_EN + 2048)           // 131072 ints
#define WS_NEED   (WS_ROWS + 524288)
#define WS_FLAGS  8

typedef __attribute__((ext_vector_type(8))) short bf16x8;
typedef __attribute__((ext_vector_type(4))) float f32x4;

__device__ __forceinline__ float bf2f(unsigned short u) {
    return __uint_as_float(((unsigned)u) << 16);
}

__device__ __forceinline__ void splitA(const float4& a0, const float4& a1,
                                       bf16x8& ah, bf16x8& al) {
    float ff[8] = {a0.x, a0.y, a0.z, a0.w, a1.x, a1.y, a1.z, a1.w};
    #pragma unroll
    for (int j = 0; j < 8; ++j) {
        unsigned u = __float_as_uint(ff[j]);
        ah[j] = (short)(u >> 16);
        float r = ff[j] - __uint_as_float(u & 0xffff0000u);
        al[j] = (short)(__float_as_uint(r) >> 16);
    }
}

// ============ K1: split codebook + norms (wave0) + i64 + group count ============
__global__ void vq_prep2(const float* __restrict__ cbf, const int* __restrict__ nt,
                         unsigned short* __restrict__ cbh, unsigned short* __restrict__ cbl,
                         float* __restrict__ eN, int* __restrict__ gcnt) {
    __shared__ int sI64, c4[4];
    const int bid = blockIdx.x;      // 512
    const int tid = threadIdx.x;     // 256

    if (tid < 4) c4[tid] = 0;

    if (tid < 64) {                  // wave 0: split code=bid
        const int lane = tid;
        float4 v = *(const float4*)(cbf + bid * 256 + lane * 4);
        unsigned u0 = __float_as_uint(v.x), u1 = __float_as_uint(v.y);
        unsigned u2 = __float_as_uint(v.z), u3 = __float_as_uint(v.w);
        ushort4 h = make_ushort4((unsigned short)(u0 >> 16), (unsigned short)(u1 >> 16),
                                 (unsigned short)(u2 >> 16), (unsigned short)(u3 >> 16));
        float r0 = v.x - __uint_as_float(u0 & 0xffff0000u);
        float r1 = v.y - __uint_as_float(u1 & 0xffff0000u);
        float r2 = v.z - __uint_as_float(u2 & 0xffff0000u);
        float r3 = v.w - __uint_as_float(u3 & 0xffff0000u);
        ushort4 l = make_ushort4((unsigned short)(__float_as_uint(r0) >> 16),
                                 (unsigned short)(__float_as_uint(r1) >> 16),
                                 (unsigned short)(__float_as_uint(r2) >> 16),
                                 (unsigned short)(__float_as_uint(r3) >> 16));
        *(ushort4*)(cbh + bid * 256 + lane * 4) = h;
        *(ushort4*)(cbl + bid * 256 + lane * 4) = l;
        float s = fmaf(v.x, v.x, fmaf(v.y, v.y, fmaf(v.z, v.z, v.w * v.w)));
        #pragma unroll
        for (int d = 1; d < 64; d <<= 1) s += __shfl_xor(s, d);
        if (lane == 0) eN[bid] = s;
    } else if (tid < 128) {          // wave 1: local i64 detect
        int o = (nt[2 * (tid - 64) + 1] != 0) ? 1 : 0;
        unsigned long long m = __ballot(o != 0);
        if (tid == 64) sI64 = (m == 0ULL) ? 1 : 0;
    }
    __syncthreads();

    const int i64 = sI64;
    const int row = bid * 256 + tid;
    const int tv  = i64 ? nt[2 * row] : nt[row];
    const int g   = (tv == 5) ? 0 : (tv == 6) ? 1 : (tv == 7) ? 2 : 3;
    atomicAdd(&c4[g], 1);
    __syncthreads();
    if (tid < 4) atomicAdd(&gcnt[tid], c4[tid]);
}

// ============ K2: scatter rows by group (off computed from complete gcnt) ============
__global__ void vq_binoff(const int* __restrict__ nt, const int* __restrict__ gcnt,
                          int* __restrict__ gposD, int* __restrict__ rows) {
    __shared__ int sI64, basev[4], pos[4];
    const int tid = threadIdx.x;
    if (tid < 4) pos[tid] = 0;
    if (tid >= 64 && tid < 128) {
        int o = (nt[2 * (tid - 64) + 1] != 0) ? 1 : 0;
        unsigned long long m = __ballot(o != 0);
        if (tid == 64) sI64 = (m == 0ULL) ? 1 : 0;
    }
    __syncthreads();
    const int i64 = sI64;
    const int row = blockIdx.x * 256 + tid;
    const int tv  = i64 ? nt[2 * row] : nt[row];
    const int g   = (tv == 5) ? 0 : (tv == 6) ? 1 : (tv == 7) ? 2 : 3;
    atomicAdd(&pos[g], 1);
    __syncthreads();
    if (tid < 4) {
        int c0 = gcnt[0], c1 = gcnt[1], c2 = gcnt[2];
        int off = (tid == 0) ? 0 : (tid == 1) ? c0 : (tid == 2) ? (c0 + c1) : (c0 + c1 + c2);
        basev[tid] = off + atomicAdd(&gposD[tid], pos[tid]);
        pos[tid] = 0;
    }
    __syncthreads();
    int p = atomicAdd(&pos[g], 1);
    rows[basev[g] + p] = row;
}

// ============ K3: scoring, 32-row tile per wave, TWO 16-row passes ============
__global__ __launch_bounds__(TPB, 4) void vq_score10(
    const float* __restrict__ zf,
    const float* __restrict__ cbf,
    const unsigned short* __restrict__ cbh,
    const unsigned short* __restrict__ cbl,
    const float* __restrict__ eN,
    const int* __restrict__ rows,
    const int* __restrict__ gcnt,
    float* __restrict__ out,
    double* __restrict__ wsum)
{
    __shared__ int2   sT[4][16];
    __shared__ float2 sM[4][16];
    __shared__ float  sZZ[4][16];
    __shared__ int    sW[4][32];
    __shared__ double sRed[4];

    const int tid  = threadIdx.x;
    const int wave = tid >> 6;
    const int lane = tid & 63;
    const int col  = lane & 15;
    const int quad = lane >> 4;
    const int w    = blockIdx.x * 4 + wave;

    // inline tile decode from group counts
    const int cnt0 = gcnt[0], cnt1 = gcnt[1], cnt2 = gcnt[2], cnt3 = gcnt[3];
    const int off1 = cnt0, off2 = off1 + cnt1, off3 = off2 + cnt2;
    const int tl0 = (cnt0 + 31) >> 5, tl1 = (cnt1 + 31) >> 5, tl2 = (cnt2 + 31) >> 5;
    const int tl3 = (cnt3 + 31) >> 5;
    const int to1 = tl0, to2 = to1 + tl1, to3 = to2 + tl2, tot = to3 + tl3;

    double lacc = 0.0;
    int nr = 0, base = 0;

    if (w < tot) {
        int g, b, offg, cntg;
        if (w < to1)      { g = 0; b = w;       offg = 0;    cntg = cnt0; }
        else if (w < to2) { g = 1; b = w - to1; offg = off1; cntg = cnt1; }
        else if (w < to3) { g = 2; b = w - to2; offg = off2; cntg = cnt2; }
        else              { g = 3; b = w - to3; offg = off3; cntg = cnt3; }
        base = offg + b * 32;
        nr = cntg - b * 32; if (nr > 32) nr = 32;

        float e8[8];
        #pragma unroll
        for (int t = 0; t < 8; ++t) e8[t] = eN[g * 128 + t * 16 + col];

        #pragma unroll 1
        for (int st = 0; st < 2; ++st) {
            const int nrs = (st == 0) ? ((nr < 16) ? nr : 16) : (nr - 16);
            if (nrs <= 0) continue;

            const int ix = base + st * 16 + ((col < nrs) ? col : (nrs - 1));
            const float* za = zf + rows[ix] * 256 + quad * 8;
            const unsigned short* bhp = cbh + (g * 128 + col) * 256 + quad * 8;
            const unsigned short* blp = cbl + (g * 128 + col) * 256 + quad * 8;

            f32x4 acc[8];
            #pragma unroll
            for (int t = 0; t < 8; ++t) acc[t] = (f32x4){0.f, 0.f, 0.f, 0.f};
            float zz = 0.f;

            #pragma unroll
            for (int c = 0; c < 8; ++c) {
                float4 a0 = *(const float4*)(za + c * 32);
                float4 a1 = *(const float4*)(za + c * 32 + 4);
                zz = fmaf(a0.x,a0.x,fmaf(a0.y,a0.y,fmaf(a0.z,a0.z,fmaf(a0.w,a0.w,zz))));
                zz = fmaf(a1.x,a1.x,fmaf(a1.y,a1.y,fmaf(a1.z,a1.z,fmaf(a1.w,a1.w,zz))));
                bf16x8 ah, al;
                splitA(a0, a1, ah, al);
                #pragma unroll
                for (int t = 0; t < 8; ++t) {
                    bf16x8 bh = *(const bf16x8*)(bhp + t * 4096 + c * 32);
                    bf16x8 bl = *(const bf16x8*)(blp + t * 4096 + c * 32);
                    acc[t] = __builtin_amdgcn_mfma_f32_16x16x32_bf16(ah, bh, acc[t], 0, 0, 0);
                    acc[t] = __builtin_amdgcn_mfma_f32_16x16x32_bf16(al, bh, acc[t], 0, 0, 0);
                    acc[t] = __builtin_amdgcn_mfma_f32_16x16x32_bf16(ah, bl, acc[t], 0, 0, 0);
                }
            }
            zz += __shfl_xor(zz, 16); zz += __shfl_xor(zz, 32);
            if (quad == 0) sZZ[wave][col] = zz;

            // ---- per-row top-2 (score = ||e||^2 - 2 z.e); C row=quad*4+r, col=lane&15 ----
            #pragma unroll
            for (int r = 0; r < 4; ++r) {
                float m1 = __builtin_inff(), m2 = __builtin_inff();
                int   i1 = 0x7fffffff,      i2 = 0x7fffffff;
                #pragma unroll
                for (int t = 0; t < 8; ++t) {
                    float sc = e8[t] - 2.f * acc[t][r];
                    int   ci = t * 16 + col;
                    if (sc < m1 || (sc == m1 && ci < i1)) { m2 = m1; i2 = i1; m1 = sc; i1 = ci; }
                    else if (sc < m2 || (sc == m2 && ci < i2)) { m2 = sc; i2 = ci; }
                }
                #pragma unroll
                for (int d2 = 1; d2 < 16; d2 <<= 1) {
                    float b1 = __shfl_xor(m1, d2);
                    int  bi1 = __shfl_xor(i1, d2);
                    float b2 = __shfl_xor(m2, d2);
                    int  bi2 = __shfl_xor(i2, d2);
                    if (b1 < m1 || (b1 == m1 && bi1 < i1)) {
                        float om = m1; int oi = i1;
                        m1 = b1; i1 = bi1;
                        if (b2 < om || (b2 == om && bi2 < oi)) { m2 = b2; i2 = bi2; }
                        else                                   { m2 = om; i2 = oi; }
                    } else {
                        if (b1 < m2 || (b1 == m2 && bi1 < i2)) { m2 = b1; i2 = bi1; }
                    }
                }
                if (col == 0) {
                    sT[wave][quad * 4 + r] = make_int2(i1, i2);
                    sM[wave][quad * 4 + r] = make_float2(m1, m2);
                }
            }

            // ---- gated epilogue (4 lanes per row): pick winner, loss, idx ----
            const int s  = lane >> 2;
            const int pq = lane & 3;
            const bool valid = (s < nrs);
            int grow = 0, c1 = 0, c2 = 0;
            float scm1 = 0.f, scm2 = 1e30f, zzr = 0.f;
            if (valid) {
                grow = rows[base + st * 16 + s];
                int2  tt = sT[wave][s];
                float2 mm = sM[wave][s];
                zzr = sZZ[wave][s];
                c1 = g * 128 + tt.x;
                c2 = g * 128 + tt.y;
                scm1 = mm.x; scm2 = mm.y;
            }
            int    wfin  = c1;
            double dfull = (double)(zzr + scm1);
            const bool need = valid && (scm2 - scm1 <= THETA);

            if (__any(need)) {        // rare: fp64 refine of close top-2
                double d1c = 0.0, d2c = 0.0;
                if (need) {
                    const float* zp = zf  + grow * 256 + pq * 64;
                    const float* p1 = cbf + c1 * 256 + pq * 64;
                    const float* p2 = cbf + c2 * 256 + pq * 64;
                    #pragma unroll 4
                    for (int it = 0; it < 16; ++it) {
                        float4 fz = *(const float4*)(zp + it * 4);
                        float4 g1 = *(const float4*)(p1 + it * 4);
                        float4 g2 = *(const float4*)(p2 + it * 4);
                        double e;
                        e = (double)fz.x - (double)g1.x; d1c = fma(e, e, d1c);
                        e = (double)fz.y - (double)g1.y; d1c = fma(e, e, d1c);
                        e = (double)fz.z - (double)g1.z; d1c = fma(e, e, d1c);
                        e = (double)fz.w - (double)g1.w; d1c = fma(e, e, d1c);
                        e = (double)fz.x - (double)g2.x; d2c = fma(e, e, d2c);
                        e = (double)fz.y - (double)g2.y; d2c = fma(e, e, d2c);
                        e = (double)fz.z - (double)g2.z; d2c = fma(e, e, d2c);
                        e = (double)fz.w - (double)g2.w; d2c = fma(e, e, d2c);
                    }
                }
                double t1 = d1c + __shfl_xor(d1c, 1); t1 += __shfl_xor(t1, 2);
                double t2 = d2c + __shfl_xor(d2c, 1); t2 += __shfl_xor(t2, 2);
                if (need) {
                    bool take1 = (t1 < t2) || (t1 == t2 && c1 < c2);
                    wfin  = take1 ? c1 : c2;
                    dfull = take1 ? t1 : t2;
                }
            }

            if (valid && pq == 0) {
                lacc += dfull;
                sW[wave][st * 16 + s] = wfin;
                out[2 + grow] = (float)wfin;
            }
        }

        // ---- wave-cooperative coalesced winner copy (1 row per iteration) ----
        for (int r = 0; r < nr; ++r) {
            const int wv  = sW[wave][r];
            const int gr2 = rows[base + r];
            const float4 v = *(const float4*)(cbf + wv * 256 + lane * 4);  // 16B aligned
            const int ob = 2 + B_ROWS + gr2 * 256;                          // == 2 mod 4
            *(float2*)(out + ob + lane * 4)     = make_float2(v.x, v.y);
            *(float2*)(out + ob + lane * 4 + 2) = make_float2(v.z, v.w);
        }
    }

    #pragma unroll
    for (int d2 = 1; d2 < 64; d2 <<= 1) lacc += __shfl_xor(lacc, d2);
    if (lane == 0) sRed[wave] = lacc;
    __syncthreads();
    if (tid == 0) atomicAdd(&wsum[blockIdx.x & 63], sRed[0] + sRed[1] + sRed[2] + sRed[3]);
}

// ===================== tiny-ws fallback (fp32 VALU path) =====================
__global__ void vq_detect(const unsigned short* cb, const int* nt, int* flag) {
    __shared__ int cnt, odd;
    if (threadIdx.x == 0) { cnt = 0; odd = 0; }
    __syncthreads();
    int c = 0, o = 0;
    for (int i = threadIdx.x; i < 512; i += 64) {
        unsigned short u = cb[2 * i];
        int e = (u >> 7) & 0xFF;
        if (e < 100 || e > 140) c++;
    }
    if (nt[2 * threadIdx.x + 1] != 0) o = 1;
    atomicAdd(&cnt, c);
    atomicAdd(&odd, o);
    __syncthreads();
    if (threadIdx.x == 0) {
        flag[0] = (cnt < 50) ? 1 : 0;
        flag[1] = (odd == 0) ? 1 : 0;
    }
}

__global__ __launch_bounds__(512, 2) void vq_main_f32(
    const int* __restrict__ nt,
    const float* __restrict__ zff,
    const float* __restrict__ cbf,
    float* __restrict__ out,
    double* __restrict__ wsum,
    const int* __restrict__ flag)
{
    if (flag[0] != 0) return;
    const int i64 = flag[1];

    __shared__ float  sE[256 * 132];
    __shared__ float  sZ[128 * 32];
    __shared__ int    sList[512];
    __shared__ int    sCnt[4], sPos[4];
    __shared__ int    sTop1[128], sTop2[128];
    __shared__ float  sEe[128];
    __shared__ double sRed[8];

    const int tid  = threadIdx.x;
    const int row0 = blockIdx.x * 512;

    if (tid < 4) { sCnt[tid] = 0; sPos[tid] = 0; }
    __syncthreads();
    {
        int t = i64 ? nt[2 * (row0 + tid)] : nt[row0 + tid];
        int g = (t == 5) ? 0 : (t == 6) ? 1 : (t == 7) ? 2 : 3;
        atomicAdd(&sCnt[g], 1);
        __syncthreads();
        int o1 = sCnt[0], o2 = o1 + sCnt[1], o3 = o2 + sCnt[2];
        int offg = (g == 0) ? 0 : (g == 1) ? o1 : (g == 2) ? o2 : o3;
        int p = atomicAdd(&sPos[g], 1);
        sList[offg + p] = row0 + tid;
    }
    __syncthreads();

    int cnt[4], off[4];
    cnt[0] = sCnt[0]; cnt[1] = sCnt[1]; cnt[2] = sCnt[2]; cnt[3] = sCnt[3];
    off[0] = 0; off[1] = cnt[0]; off[2] = off[1] + cnt[1]; off[3] = off[2] + cnt[2];

    const int ccol = tid & 31, rrow = tid >> 5;
    const int c0 = ccol * 4, rbase = rrow * 8;
    double lacc = 0.0;

    for (int gg = 0; gg < 4; ++gg) {
        const int n = cnt[gg];
        if (n == 0) continue;
        __syncthreads();
        for (int i = tid; i < 128 * 256; i += 512) {
            int c = i >> 8, k = i & 255;
            sE[k * 132 + c] = cbf[(gg * 128 + c) * 256 + k];
        }
        __syncthreads();
        if (tid < 128) {
            float s = 0.f;
            for (int k = 0; k < 256; ++k) { float v = sE[k * 132 + tid]; s = fmaf(v, v, s); }
            sEe[tid] = s;
        }
        __syncthreads();

        const int ntiles = (n + 127) >> 7;
        for (int tI = 0; tI < ntiles; ++tI) {
            const int tbase = off[gg] + tI * 128;
            const int nrows = min(128, n - tI * 128);
            float acc[8][4];
            #pragma unroll
            for (int r = 0; r < 8; ++r)
                #pragma unroll
                for (int q = 0; q < 4; ++q) acc[r][q] = 0.f;

            for (int kb = 0; kb < 8; ++kb) {
                __syncthreads();
                #pragma unroll
                for (int it = 0; it < 2; ++it) {
                    int i = it * 512 + tid;
                    int s = i >> 3, j = i & 7;
                    float4 v = make_float4(0.f, 0.f, 0.f, 0.f);
                    if (s < nrows) {
                        int gr = sList[tbase + s];
                        v = *(const float4*)(zff + gr * 256 + kb * 32 + j * 4);
                    }
                    *(float4*)&sZ[s * 32 + j * 4] = v;
                }
                __syncthreads();
                #pragma unroll
                for (int k4 = 0; k4 < 8; ++k4) {
                    const int kk = kb * 32 + k4 * 4;
                    const float4 e0 = *(const float4*)&sE[(kk + 0) * 132 + c0];
                    const float4 e1 = *(const float4*)&sE[(kk + 1) * 132 + c0];
                    const float4 e2 = *(const float4*)&sE[(kk + 2) * 132 + c0];
                    const float4 e3 = *(const float4*)&sE[(kk + 3) * 132 + c0];
                    #pragma unroll
                    for (int r = 0; r < 8; ++r) {
                        const float4 zv = *(const float4*)&sZ[(rbase + r) * 32 + k4 * 4];
                        acc[r][0] = fmaf(zv.x, e0.x, fmaf(zv.y, e1.x, fmaf(zv.z, e2.x, fmaf(zv.w, e3.x, acc[r][0]))));
                        acc[r][1] = fmaf(zv.x, e0.y, fmaf(zv.y, e1.y, fmaf(zv.z, e2.y, fmaf(zv.w, e3.y, acc[r][1]))));
                        acc[r][2] = fmaf(zv.x, e0.z, fmaf(zv.y, e1.z, fmaf(zv.z, e2.z, fmaf(zv.w, e3.z, acc[r][2]))));
                        acc[r][3] = fmaf(zv.x, e0.w, fmaf(zv.y, e1.w, fmaf(zv.z, e2.w, fmaf(zv.w, e3.w, acc[r][3]))));
                    }
                }
            }

            float eq[4] = { sEe[c0], sEe[c0 + 1], sEe[c0 + 2], sEe[c0 + 3] };
            for (int r = 0; r < 8; ++r) {
                float m1 = __builtin_inff(), m2 = __builtin_inff();
                int   i1 = 0x7fffffff,      i2 = 0x7fffffff;
                #pragma unroll
                for (int q = 0; q < 4; ++q) {
                    float sc = eq[q] - 2.f * acc[r][q];
                    int   ci = c0 + q;
                    if (sc < m1 || (sc == m1 && ci < i1)) { m2 = m1; i2 = i1; m1 = sc; i1 = ci; }
                    else if (sc < m2 || (sc == m2 && ci < i2)) { m2 = sc; i2 = ci; }
                }
                #pragma unroll
                for (int d = 1; d < 32; d <<= 1) {
                    float b1 = __shfl_xor(m1, d);
                    int  bi1 = __shfl_xor(i1, d);
                    float b2 = __shfl_xor(m2, d);
                    int  bi2 = __shfl_xor(i2, d);
                    if (b1 < m1 || (b1 == m1 && bi1 < i1)) {
                        float om = m1; int oi = i1;
                        m1 = b1; i1 = bi1;
                        if (b2 < om || (b2 == om && bi2 < oi)) { m2 = b2; i2 = bi2; }
                        else                                   { m2 = om; i2 = oi; }
                    } else {
                        if (b1 < m2 || (b1 == m2 && bi1 < i2)) { m2 = b1; i2 = bi1; }
                    }
                }
                if (ccol == 0) { sTop1[rbase + r] = i1; sTop2[rbase + r] = i2; }
            }
            __syncthreads();

            {
                const int s  = tid >> 2;
                const int pq = tid & 3;
                const bool valid = (s < nrows);
                double d1c = 0.0, d2c = 0.0;
                int gr = 0, c1g = 0, c2g = 0;
                if (valid) {
                    gr  = sList[tbase + s];
                    c1g = gg * 128 + sTop1[s];
                    c2g = gg * 128 + sTop2[s];
                    #pragma unroll 4
                    for (int it = 0; it < 16; ++it) {
                        float4 fz = *(const float4*)(zff + gr  * 256 + pq * 64 + it * 4);
                        float4 f1 = *(const float4*)(cbf + c1g * 256 + pq * 64 + it * 4);
                        float4 f2 = *(const float4*)(cbf + c2g * 256 + pq * 64 + it * 4);
                        double e;
                        e = (double)fz.x - (double)f1.x; d1c = fma(e, e, d1c);
                        e = (double)fz.y - (double)f1.y; d1c = fma(e, e, d1c);
                        e = (double)fz.z - (double)f1.z; d1c = fma(e, e, d1c);
                        e = (double)fz.w - (double)f1.w; d1c = fma(e, e, d1c);
                        e = (double)fz.x - (double)f2.x; d2c = fma(e, e, d2c);
                        e = (double)fz.y - (double)f2.y; d2c = fma(e, e, d2c);
                        e = (double)fz.z - (double)f2.z; d2c = fma(e, e, d2c);
                        e = (double)fz.w - (double)f2.w; d2c = fma(e, e, d2c);
                    }
                }
                double t1 = d1c + __shfl_xor(d1c, 1); t1 += __shfl_xor(t1, 2);
                double t2 = d2c + __shfl_xor(d2c, 1); t2 += __shfl_xor(t2, 2);
                if (valid) {
                    bool take1 = (t1 < t2) || (t1 == t2 && c1g < c2g);
                    int  w = take1 ? c1g : c2g;
                    lacc += take1 ? d1c : d2c;
                    const int obase = 2 + B_ROWS + gr * 256 + pq * 64;
                    #pragma unroll 4
                    for (int it = 0; it < 16; ++it) {
                        float4 f4 = *(const float4*)(cbf + w * 256 + pq * 64 + it * 4);
                        *(float2*)(out + obase + it * 4)     = make_float2(f4.x, f4.y);
                        *(float2*)(out + obase + it * 4 + 2) = make_float2(f4.z, f4.w);
                    }
                    if (pq == 0) out[2 + gr] = (float)w;
                }
            }
        }
    }

    #pragma unroll
    for (int d = 1; d < 64; d <<= 1) lacc += __shfl_xor(lacc, d);
    if ((tid & 63) == 0) sRed[tid >> 6] = lacc;
    __syncthreads();
    if (tid == 0) {
        double s = 0.0;
        #pragma unroll
        for (int i = 0; i < 8; ++i) s += sRed[i];
        atomicAdd(wsum, s);
    }
}

__global__ void vq_fin(const double* wsum, float* out, int n) {
    if (threadIdx.x == 0 && blockIdx.x == 0) {
        double m = 0.0;
        for (int i = 0; i < n; ++i) m += wsum[i];
        m /= ((double)B_ROWS * (double)D_EMB);
        out[0] = (float)m;
        out[1] = (float)(0.25 * m);
    }
}

extern "C" void kernel_launch(void* const* d_in, const int* in_sizes, int n_in,
                              void* d_out, int out_size, void* d_ws, size_t ws_size,
                              hipStream_t stream) {
    const int*   nt  = (const int*)d_in[0];
    const float* zf  = (const float*)d_in[1];
    const float* cbf = (const float*)d_in[2];
    float*  out  = (float*)d_out;
    double* wsum = (double*)((char*)d_ws + WS_WSUM);

    hipMemsetAsync(d_ws, 0, 1024, stream);

    if (ws_size >= (size_t)WS_NEED) {
        unsigned short* cbh  = (unsigned short*)((char*)d_ws + WS_CBH);
        unsigned short* cbl  = (unsigned short*)((char*)d_ws + WS_CBL);
        float* eN    = (float*)((char*)d_ws + WS_EN);
        int*   gcnt  = (int*)((char*)d_ws + WS_GCNT);
        int*   gposD = (int*)((char*)d_ws + WS_GPOSD);
        int*   rowsp = (int*)((char*)d_ws + WS_ROWS);
        vq_prep2<<<512, 256, 0, stream>>>(cbf, nt, cbh, cbl, eN, gcnt);
        vq_binoff<<<512, 256, 0, stream>>>(nt, gcnt, gposD, rowsp);
        vq_score10<<<SGRID, TPB, 0, stream>>>(zf, cbf, cbh, cbl, eN, rowsp, gcnt,
                                              out, wsum);
        vq_fin<<<1, 64, 0, stream>>>(wsum, out, 64);
    } else {
        int* flag = (int*)((char*)d_ws + WS_FLAGS);
        vq_detect<<<1, 64, 0, stream>>>((const unsigned short*)cbf, nt, flag);
        vq_main_f32<<<256, 512, 0, stream>>>(nt, zf, cbf, out, wsum, flag);
        vq_fin<<<1, 64, 0, stream>>>(wsum, out, 1);
    }
}

// Round 13
// 383.504 us; speedup vs baseline: 2.0058x; 1.4790x over previous
//
#include <hip/hip_runtime.h>

// VectorQuantizer on MI355X. d_out = FLOAT32 concat:
// [0]=vq_loss, [1]=commitment, [2..2+B)=idx(float), [2+B..)=quantized (B x 256).
// Round 13: R12 retry (compile fix). NT stores need native clang vector types:
// use ext_vector_type(2) float for the pair stores (HIP_vector_type rejected).
// Theory unchanged: output is write-once -> NT stores bypass L2/L3, killing
// write amplification (WRITE ~1.5x ideal in R7-R11) and read-set eviction.

#define B_ROWS   131072
#define D_EMB    256
#define TPB      256
#define SGRID    1025                 // 1025 blocks x 4 waves >= max 4100 tiles
#define THETA    0.0625f

// ---- workspace layout (bytes) ----
#define WS_WSUM   0                        // 64 doubles (512B)
#define WS_GCNT   516                      // 4 ints
#define WS_GPOSD  532                      // 4 ints (scatter cursors)
#define WS_CBH    1024                     // 512*256 bf16 hi (262144B)
#define WS_CBL    (WS_CBH + 262144)        // bf16 lo
#define WS_EN     (WS_CBL + 262144)        // 512 f32 norms
#define WS_ROWS   (WS_EN + 2048)           // 131072 ints
#define WS_NEED   (WS_ROWS + 524288)
#define WS_FLAGS  8

typedef __attribute__((ext_vector_type(8))) short bf16x8;
typedef __attribute__((ext_vector_type(4))) float f32x4;
typedef __attribute__((ext_vector_type(2))) float f32x2;   // NT-store compatible

__device__ __forceinline__ float bf2f(unsigned short u) {
    return __uint_as_float(((unsigned)u) << 16);
}

__device__ __forceinline__ void splitA(const float4& a0, const float4& a1,
                                       bf16x8& ah, bf16x8& al) {
    float ff[8] = {a0.x, a0.y, a0.z, a0.w, a1.x, a1.y, a1.z, a1.w};
    #pragma unroll
    for (int j = 0; j < 8; ++j) {
        unsigned u = __float_as_uint(ff[j]);
        ah[j] = (short)(u >> 16);
        float r = ff[j] - __uint_as_float(u & 0xffff0000u);
        al[j] = (short)(__float_as_uint(r) >> 16);
    }
}

// ============ K1: split codebook + norms (wave0) + i64 + group count ============
__global__ void vq_prep2(const float* __restrict__ cbf, const int* __restrict__ nt,
                         unsigned short* __restrict__ cbh, unsigned short* __restrict__ cbl,
                         float* __restrict__ eN, int* __restrict__ gcnt) {
    __shared__ int sI64, c4[4];
    const int bid = blockIdx.x;      // 512
    const int tid = threadIdx.x;     // 256

    if (tid < 4) c4[tid] = 0;

    if (tid < 64) {                  // wave 0: split code=bid
        const int lane = tid;
        float4 v = *(const float4*)(cbf + bid * 256 + lane * 4);
        unsigned u0 = __float_as_uint(v.x), u1 = __float_as_uint(v.y);
        unsigned u2 = __float_as_uint(v.z), u3 = __float_as_uint(v.w);
        ushort4 h = make_ushort4((unsigned short)(u0 >> 16), (unsigned short)(u1 >> 16),
                                 (unsigned short)(u2 >> 16), (unsigned short)(u3 >> 16));
        float r0 = v.x - __uint_as_float(u0 & 0xffff0000u);
        float r1 = v.y - __uint_as_float(u1 & 0xffff0000u);
        float r2 = v.z - __uint_as_float(u2 & 0xffff0000u);
        float r3 = v.w - __uint_as_float(u3 & 0xffff0000u);
        ushort4 l = make_ushort4((unsigned short)(__float_as_uint(r0) >> 16),
                                 (unsigned short)(__float_as_uint(r1) >> 16),
                                 (unsigned short)(__float_as_uint(r2) >> 16),
                                 (unsigned short)(__float_as_uint(r3) >> 16));
        *(ushort4*)(cbh + bid * 256 + lane * 4) = h;
        *(ushort4*)(cbl + bid * 256 + lane * 4) = l;
        float s = fmaf(v.x, v.x, fmaf(v.y, v.y, fmaf(v.z, v.z, v.w * v.w)));
        #pragma unroll
        for (int d = 1; d < 64; d <<= 1) s += __shfl_xor(s, d);
        if (lane == 0) eN[bid] = s;
    } else if (tid < 128) {          // wave 1: local i64 detect
        int o = (nt[2 * (tid - 64) + 1] != 0) ? 1 : 0;
        unsigned long long m = __ballot(o != 0);
        if (tid == 64) sI64 = (m == 0ULL) ? 1 : 0;
    }
    __syncthreads();

    const int i64 = sI64;
    const int row = bid * 256 + tid;
    const int tv  = i64 ? nt[2 * row] : nt[row];
    const int g   = (tv == 5) ? 0 : (tv == 6) ? 1 : (tv == 7) ? 2 : 3;
    atomicAdd(&c4[g], 1);
    __syncthreads();
    if (tid < 4) atomicAdd(&gcnt[tid], c4[tid]);
}

// ============ K2: scatter rows by group (off computed from complete gcnt) ============
__global__ void vq_binoff(const int* __restrict__ nt, const int* __restrict__ gcnt,
                          int* __restrict__ gposD, int* __restrict__ rows) {
    __shared__ int sI64, basev[4], pos[4];
    const int tid = threadIdx.x;
    if (tid < 4) pos[tid] = 0;
    if (tid >= 64 && tid < 128) {
        int o = (nt[2 * (tid - 64) + 1] != 0) ? 1 : 0;
        unsigned long long m = __ballot(o != 0);
        if (tid == 64) sI64 = (m == 0ULL) ? 1 : 0;
    }
    __syncthreads();
    const int i64 = sI64;
    const int row = blockIdx.x * 256 + tid;
    const int tv  = i64 ? nt[2 * row] : nt[row];
    const int g   = (tv == 5) ? 0 : (tv == 6) ? 1 : (tv == 7) ? 2 : 3;
    atomicAdd(&pos[g], 1);
    __syncthreads();
    if (tid < 4) {
        int c0 = gcnt[0], c1 = gcnt[1], c2 = gcnt[2];
        int off = (tid == 0) ? 0 : (tid == 1) ? c0 : (tid == 2) ? (c0 + c1) : (c0 + c1 + c2);
        basev[tid] = off + atomicAdd(&gposD[tid], pos[tid]);
        pos[tid] = 0;
    }
    __syncthreads();
    int p = atomicAdd(&pos[g], 1);
    rows[basev[g] + p] = row;
}

// ============ K3: scoring, one 32x128 tile per wave (R7 body) + NT stores ============
__global__ __launch_bounds__(TPB, 3) void vq_score11(
    const float* __restrict__ zf,
    const float* __restrict__ cbf,
    const unsigned short* __restrict__ cbh,
    const unsigned short* __restrict__ cbl,
    const float* __restrict__ eN,
    const int* __restrict__ rows,
    const int* __restrict__ gcnt,
    float* __restrict__ out,
    double* __restrict__ wsum)
{
    __shared__ int2   sT[4][16];
    __shared__ float2 sM[4][16];
    __shared__ float  sZZ[4][16];
    __shared__ int    sW[4][32];
    __shared__ double sRed[4];

    const int tid  = threadIdx.x;
    const int wave = tid >> 6;
    const int lane = tid & 63;
    const int col  = lane & 15;
    const int quad = lane >> 4;
    const int w    = blockIdx.x * 4 + wave;

    // inline tile decode from group counts
    const int cnt0 = gcnt[0], cnt1 = gcnt[1], cnt2 = gcnt[2], cnt3 = gcnt[3];
    const int off1 = cnt0, off2 = off1 + cnt1, off3 = off2 + cnt2;
    const int tl0 = (cnt0 + 31) >> 5, tl1 = (cnt1 + 31) >> 5, tl2 = (cnt2 + 31) >> 5;
    const int tl3 = (cnt3 + 31) >> 5;
    const int to1 = tl0, to2 = to1 + tl1, to3 = to2 + tl2, tot = to3 + tl3;

    double lacc = 0.0;

    if (w < tot) {
        int g, b, offg, cntg;
        if (w < to1)      { g = 0; b = w;       offg = 0;    cntg = cnt0; }
        else if (w < to2) { g = 1; b = w - to1; offg = off1; cntg = cnt1; }
        else if (w < to3) { g = 2; b = w - to2; offg = off2; cntg = cnt2; }
        else              { g = 3; b = w - to3; offg = off3; cntg = cnt3; }
        const int base = offg + b * 32;
        int nr = cntg - b * 32; if (nr > 32) nr = 32;
        const int nr0  = (nr < 16) ? nr : 16;
        const int nr1  = nr - 16;

        int ix0 = base + ((col < nr0) ? col : (nr0 - 1));
        int ix1 = (nr1 > 0) ? (base + 16 + ((col < nr1) ? col : (nr1 - 1))) : ix0;
        const float* za0 = zf + rows[ix0] * 256 + quad * 8;
        const float* za1 = zf + rows[ix1] * 256 + quad * 8;
        const unsigned short* bhp = cbh + (g * 128 + col) * 256 + quad * 8;
        const unsigned short* blp = cbl + (g * 128 + col) * 256 + quad * 8;

        f32x4 acc[2][8];
        #pragma unroll
        for (int st = 0; st < 2; ++st)
            #pragma unroll
            for (int t = 0; t < 8; ++t) acc[st][t] = (f32x4){0.f, 0.f, 0.f, 0.f};
        float zz0 = 0.f, zz1 = 0.f;

        #pragma unroll
        for (int c = 0; c < 8; ++c) {
            float4 a00 = *(const float4*)(za0 + c * 32);
            float4 a01 = *(const float4*)(za0 + c * 32 + 4);
            float4 a10 = *(const float4*)(za1 + c * 32);
            float4 a11 = *(const float4*)(za1 + c * 32 + 4);
            zz0 = fmaf(a00.x,a00.x,fmaf(a00.y,a00.y,fmaf(a00.z,a00.z,fmaf(a00.w,a00.w,zz0))));
            zz0 = fmaf(a01.x,a01.x,fmaf(a01.y,a01.y,fmaf(a01.z,a01.z,fmaf(a01.w,a01.w,zz0))));
            zz1 = fmaf(a10.x,a10.x,fmaf(a10.y,a10.y,fmaf(a10.z,a10.z,fmaf(a10.w,a10.w,zz1))));
            zz1 = fmaf(a11.x,a11.x,fmaf(a11.y,a11.y,fmaf(a11.z,a11.z,fmaf(a11.w,a11.w,zz1))));
            bf16x8 ah0, al0, ah1, al1;
            splitA(a00, a01, ah0, al0);
            splitA(a10, a11, ah1, al1);
            #pragma unroll
            for (int t = 0; t < 8; ++t) {
                bf16x8 bh = *(const bf16x8*)(bhp + t * 4096 + c * 32);
                bf16x8 bl = *(const bf16x8*)(blp + t * 4096 + c * 32);
                acc[0][t] = __builtin_amdgcn_mfma_f32_16x16x32_bf16(ah0, bh, acc[0][t], 0, 0, 0);
                acc[0][t] = __builtin_amdgcn_mfma_f32_16x16x32_bf16(al0, bh, acc[0][t], 0, 0, 0);
                acc[0][t] = __builtin_amdgcn_mfma_f32_16x16x32_bf16(ah0, bl, acc[0][t], 0, 0, 0);
                acc[1][t] = __builtin_amdgcn_mfma_f32_16x16x32_bf16(ah1, bh, acc[1][t], 0, 0, 0);
                acc[1][t] = __builtin_amdgcn_mfma_f32_16x16x32_bf16(al1, bh, acc[1][t], 0, 0, 0);
                acc[1][t] = __builtin_amdgcn_mfma_f32_16x16x32_bf16(ah1, bl, acc[1][t], 0, 0, 0);
            }
        }
        zz0 += __shfl_xor(zz0, 16); zz0 += __shfl_xor(zz0, 32);
        zz1 += __shfl_xor(zz1, 16); zz1 += __shfl_xor(zz1, 32);

        float e8[8];
        #pragma unroll
        for (int t = 0; t < 8; ++t) e8[t] = eN[g * 128 + t * 16 + col];

        for (int st = 0; st < 2; ++st) {
            const int nrs = st ? nr1 : nr0;
            if (nrs <= 0) continue;
            if (quad == 0) sZZ[wave][col] = st ? zz1 : zz0;

            // ---- per-row top-2 (score = ||e||^2 - 2 z.e); C row=quad*4+r, col=lane&15 ----
            #pragma unroll
            for (int r = 0; r < 4; ++r) {
                float m1 = __builtin_inff(), m2 = __builtin_inff();
                int   i1 = 0x7fffffff,      i2 = 0x7fffffff;
                #pragma unroll
                for (int t = 0; t < 8; ++t) {
                    float sc = e8[t] - 2.f * acc[st][t][r];
                    int   ci = t * 16 + col;
                    if (sc < m1 || (sc == m1 && ci < i1)) { m2 = m1; i2 = i1; m1 = sc; i1 = ci; }
                    else if (sc < m2 || (sc == m2 && ci < i2)) { m2 = sc; i2 = ci; }
                }
                #pragma unroll
                for (int d2 = 1; d2 < 16; d2 <<= 1) {
                    float b1 = __shfl_xor(m1, d2);
                    int  bi1 = __shfl_xor(i1, d2);
                    float b2 = __shfl_xor(m2, d2);
                    int  bi2 = __shfl_xor(i2, d2);
                    if (b1 < m1 || (b1 == m1 && bi1 < i1)) {
                        float om = m1; int oi = i1;
                        m1 = b1; i1 = bi1;
                        if (b2 < om || (b2 == om && bi2 < oi)) { m2 = b2; i2 = bi2; }
                        else                                   { m2 = om; i2 = oi; }
                    } else {
                        if (b1 < m2 || (b1 == m2 && bi1 < i2)) { m2 = b1; i2 = bi1; }
                    }
                }
                if (col == 0) {
                    sT[wave][quad * 4 + r] = make_int2(i1, i2);
                    sM[wave][quad * 4 + r] = make_float2(m1, m2);
                }
            }

            // ---- gated epilogue (4 lanes per row): pick winner, loss, idx ----
            const int s  = lane >> 2;
            const int pq = lane & 3;
            const bool valid = (s < nrs);
            int grow = 0, c1 = 0, c2 = 0;
            float scm1 = 0.f, scm2 = 1e30f, zzr = 0.f;
            if (valid) {
                grow = rows[base + st * 16 + s];
                int2  tt = sT[wave][s];
                float2 mm = sM[wave][s];
                zzr = sZZ[wave][s];
                c1 = g * 128 + tt.x;
                c2 = g * 128 + tt.y;
                scm1 = mm.x; scm2 = mm.y;
            }
            int    wfin  = c1;
            double dfull = (double)(zzr + scm1);
            const bool need = valid && (scm2 - scm1 <= THETA);

            if (__any(need)) {        // rare: fp64 refine of close top-2
                double d1c = 0.0, d2c = 0.0;
                if (need) {
                    const float* zp = zf  + grow * 256 + pq * 64;
                    const float* p1 = cbf + c1 * 256 + pq * 64;
                    const float* p2 = cbf + c2 * 256 + pq * 64;
                    #pragma unroll 4
                    for (int it = 0; it < 16; ++it) {
                        float4 fz = *(const float4*)(zp + it * 4);
                        float4 g1 = *(const float4*)(p1 + it * 4);
                        float4 g2 = *(const float4*)(p2 + it * 4);
                        double e;
                        e = (double)fz.x - (double)g1.x; d1c = fma(e, e, d1c);
                        e = (double)fz.y - (double)g1.y; d1c = fma(e, e, d1c);
                        e = (double)fz.z - (double)g1.z; d1c = fma(e, e, d1c);
                        e = (double)fz.w - (double)g1.w; d1c = fma(e, e, d1c);
                        e = (double)fz.x - (double)g2.x; d2c = fma(e, e, d2c);
                        e = (double)fz.y - (double)g2.y; d2c = fma(e, e, d2c);
                        e = (double)fz.z - (double)g2.z; d2c = fma(e, e, d2c);
                        e = (double)fz.w - (double)g2.w; d2c = fma(e, e, d2c);
                    }
                }
                double t1 = d1c + __shfl_xor(d1c, 1); t1 += __shfl_xor(t1, 2);
                double t2 = d2c + __shfl_xor(d2c, 1); t2 += __shfl_xor(t2, 2);
                if (need) {
                    bool take1 = (t1 < t2) || (t1 == t2 && c1 < c2);
                    wfin  = take1 ? c1 : c2;
                    dfull = take1 ? t1 : t2;
                }
            }

            if (valid && pq == 0) {
                lacc += dfull;
                sW[wave][st * 16 + s] = wfin;
                __builtin_nontemporal_store((float)wfin, out + 2 + grow);
            }
        }

        // ---- wave-cooperative coalesced winner copy, non-temporal stores ----
        for (int r = 0; r < nr; ++r) {
            const int wv  = sW[wave][r];
            const int gr2 = rows[base + r];
            const float4 v = *(const float4*)(cbf + wv * 256 + lane * 4);  // 16B aligned
            const int ob = 2 + B_ROWS + gr2 * 256;                          // == 2 mod 4
            f32x2 lo; lo.x = v.x; lo.y = v.y;
            f32x2 hi; hi.x = v.z; hi.y = v.w;
            __builtin_nontemporal_store(lo, (f32x2*)(out + ob + lane * 4));
            __builtin_nontemporal_store(hi, (f32x2*)(out + ob + lane * 4 + 2));
        }
    }

    #pragma unroll
    for (int d2 = 1; d2 < 64; d2 <<= 1) lacc += __shfl_xor(lacc, d2);
    if (lane == 0) sRed[wave] = lacc;
    __syncthreads();
    if (tid == 0) atomicAdd(&wsum[blockIdx.x & 63], sRed[0] + sRed[1] + sRed[2] + sRed[3]);
}

// ===================== tiny-ws fallback (fp32 VALU path) =====================
__global__ void vq_detect(const unsigned short* cb, const int* nt, int* flag) {
    __shared__ int cnt, odd;
    if (threadIdx.x == 0) { cnt = 0; odd = 0; }
    __syncthreads();
    int c = 0, o = 0;
    for (int i = threadIdx.x; i < 512; i += 64) {
        unsigned short u = cb[2 * i];
        int e = (u >> 7) & 0xFF;
        if (e < 100 || e > 140) c++;
    }
    if (nt[2 * threadIdx.x + 1] != 0) o = 1;
    atomicAdd(&cnt, c);
    atomicAdd(&odd, o);
    __syncthreads();
    if (threadIdx.x == 0) {
        flag[0] = (cnt < 50) ? 1 : 0;
        flag[1] = (odd == 0) ? 1 : 0;
    }
}

__global__ __launch_bounds__(512, 2) void vq_main_f32(
    const int* __restrict__ nt,
    const float* __restrict__ zff,
    const float* __restrict__ cbf,
    float* __restrict__ out,
    double* __restrict__ wsum,
    const int* __restrict__ flag)
{
    if (flag[0] != 0) return;
    const int i64 = flag[1];

    __shared__ float  sE[256 * 132];
    __shared__ float  sZ[128 * 32];
    __shared__ int    sList[512];
    __shared__ int    sCnt[4], sPos[4];
    __shared__ int    sTop1[128], sTop2[128];
    __shared__ float  sEe[128];
    __shared__ double sRed[8];

    const int tid  = threadIdx.x;
    const int row0 = blockIdx.x * 512;

    if (tid < 4) { sCnt[tid] = 0; sPos[tid] = 0; }
    __syncthreads();
    {
        int t = i64 ? nt[2 * (row0 + tid)] : nt[row0 + tid];
        int g = (t == 5) ? 0 : (t == 6) ? 1 : (t == 7) ? 2 : 3;
        atomicAdd(&sCnt[g], 1);
        __syncthreads();
        int o1 = sCnt[0], o2 = o1 + sCnt[1], o3 = o2 + sCnt[2];
        int offg = (g == 0) ? 0 : (g == 1) ? o1 : (g == 2) ? o2 : o3;
        int p = atomicAdd(&sPos[g], 1);
        sList[offg + p] = row0 + tid;
    }
    __syncthreads();

    int cnt[4], off[4];
    cnt[0] = sCnt[0]; cnt[1] = sCnt[1]; cnt[2] = sCnt[2]; cnt[3] = sCnt[3];
    off[0] = 0; off[1] = cnt[0]; off[2] = off[1] + cnt[1]; off[3] = off[2] + cnt[2];

    const int ccol = tid & 31, rrow = tid >> 5;
    const int c0 = ccol * 4, rbase = rrow * 8;
    double lacc = 0.0;

    for (int gg = 0; gg < 4; ++gg) {
        const int n = cnt[gg];
        if (n == 0) continue;
        __syncthreads();
        for (int i = tid; i < 128 * 256; i += 512) {
            int c = i >> 8, k = i & 255;
            sE[k * 132 + c] = cbf[(gg * 128 + c) * 256 + k];
        }
        __syncthreads();
        if (tid < 128) {
            float s = 0.f;
            for (int k = 0; k < 256; ++k) { float v = sE[k * 132 + tid]; s = fmaf(v, v, s); }
            sEe[tid] = s;
        }
        __syncthreads();

        const int ntiles = (n + 127) >> 7;
        for (int tI = 0; tI < ntiles; ++tI) {
            const int tbase = off[gg] + tI * 128;
            const int nrows = min(128, n - tI * 128);
            float acc[8][4];
            #pragma unroll
            for (int r = 0; r < 8; ++r)
                #pragma unroll
                for (int q = 0; q < 4; ++q) acc[r][q] = 0.f;

            for (int kb = 0; kb < 8; ++kb) {
                __syncthreads();
                #pragma unroll
                for (int it = 0; it < 2; ++it) {
                    int i = it * 512 + tid;
                    int s = i >> 3, j = i & 7;
                    float4 v = make_float4(0.f, 0.f, 0.f, 0.f);
                    if (s < nrows) {
                        int gr = sList[tbase + s];
                        v = *(const float4*)(zff + gr * 256 + kb * 32 + j * 4);
                    }
                    *(float4*)&sZ[s * 32 + j * 4] = v;
                }
                __syncthreads();
                #pragma unroll
                for (int k4 = 0; k4 < 8; ++k4) {
                    const int kk = kb * 32 + k4 * 4;
                    const float4 e0 = *(const float4*)&sE[(kk + 0) * 132 + c0];
                    const float4 e1 = *(const float4*)&sE[(kk + 1) * 132 + c0];
                    const float4 e2 = *(const float4*)&sE[(kk + 2) * 132 + c0];
                    const float4 e3 = *(const float4*)&sE[(kk + 3) * 132 + c0];
                    #pragma unroll
                    for (int r = 0; r < 8; ++r) {
                        const float4 zv = *(const float4*)&sZ[(rbase + r) * 32 + k4 * 4];
                        acc[r][0] = fmaf(zv.x, e0.x, fmaf(zv.y, e1.x, fmaf(zv.z, e2.x, fmaf(zv.w, e3.x, acc[r][0]))));
                        acc[r][1] = fmaf(zv.x, e0.y, fmaf(zv.y, e1.y, fmaf(zv.z, e2.y, fmaf(zv.w, e3.y, acc[r][1]))));
                        acc[r][2] = fmaf(zv.x, e0.z, fmaf(zv.y, e1.z, fmaf(zv.z, e2.z, fmaf(zv.w, e3.z, acc[r][2]))));
                        acc[r][3] = fmaf(zv.x, e0.w, fmaf(zv.y, e1.w, fmaf(zv.z, e2.w, fmaf(zv.w, e3.w, acc[r][3]))));
                    }
                }
            }

            float eq[4] = { sEe[c0], sEe[c0 + 1], sEe[c0 + 2], sEe[c0 + 3] };
            for (int r = 0; r < 8; ++r) {
                float m1 = __builtin_inff(), m2 = __builtin_inff();
                int   i1 = 0x7fffffff,      i2 = 0x7fffffff;
                #pragma unroll
                for (int q = 0; q < 4; ++q) {
                    float sc = eq[q] - 2.f * acc[r][q];
                    int   ci = c0 + q;
                    if (sc < m1 || (sc == m1 && ci < i1)) { m2 = m1; i2 = i1; m1 = sc; i1 = ci; }
                    else if (sc < m2 || (sc == m2 && ci < i2)) { m2 = sc; i2 = ci; }
                }
                #pragma unroll
                for (int d = 1; d < 32; d <<= 1) {
                    float b1 = __shfl_xor(m1, d);
                    int  bi1 = __shfl_xor(i1, d);
                    float b2 = __shfl_xor(m2, d);
                    int  bi2 = __shfl_xor(i2, d);
                    if (b1 < m1 || (b1 == m1 && bi1 < i1)) {
                        float om = m1; int oi = i1;
                        m1 = b1; i1 = bi1;
                        if (b2 < om || (b2 == om && bi2 < oi)) { m2 = b2; i2 = bi2; }
                        else                                   { m2 = om; i2 = oi; }
                    } else {
                        if (b1 < m2 || (b1 == m2 && bi1 < i2)) { m2 = b1; i2 = bi1; }
                    }
                }
                if (ccol == 0) { sTop1[rbase + r] = i1; sTop2[rbase + r] = i2; }
            }
            __syncthreads();

            {
                const int s  = tid >> 2;
                const int pq = tid & 3;
                const bool valid = (s < nrows);
                double d1c = 0.0, d2c = 0.0;
                int gr = 0, c1g = 0, c2g = 0;
                if (valid) {
                    gr  = sList[tbase + s];
                    c1g = gg * 128 + sTop1[s];
                    c2g = gg * 128 + sTop2[s];
                    #pragma unroll 4
                    for (int it = 0; it < 16; ++it) {
                        float4 fz = *(const float4*)(zff + gr  * 256 + pq * 64 + it * 4);
                        float4 f1 = *(const float4*)(cbf + c1g * 256 + pq * 64 + it * 4);
                        float4 f2 = *(const float4*)(cbf + c2g * 256 + pq * 64 + it * 4);
                        double e;
                        e = (double)fz.x - (double)f1.x; d1c = fma(e, e, d1c);
                        e = (double)fz.y - (double)f1.y; d1c = fma(e, e, d1c);
                        e = (double)fz.z - (double)f1.z; d1c = fma(e, e, d1c);
                        e = (double)fz.w - (double)f1.w; d1c = fma(e, e, d1c);
                        e = (double)fz.x - (double)f2.x; d2c = fma(e, e, d2c);
                        e = (double)fz.y - (double)f2.y; d2c = fma(e, e, d2c);
                        e = (double)fz.z - (double)f2.z; d2c = fma(e, e, d2c);
                        e = (double)fz.w - (double)f2.w; d2c = fma(e, e, d2c);
                    }
                }
                double t1 = d1c + __shfl_xor(d1c, 1); t1 += __shfl_xor(t1, 2);
                double t2 = d2c + __shfl_xor(d2c, 1); t2 += __shfl_xor(t2, 2);
                if (valid) {
                    bool take1 = (t1 < t2) || (t1 == t2 && c1g < c2g);
                    int  w = take1 ? c1g : c2g;
                    lacc += take1 ? d1c : d2c;
                    const int obase = 2 + B_ROWS + gr * 256 + pq * 64;
                    #pragma unroll 4
                    for (int it = 0; it < 16; ++it) {
                        float4 f4 = *(const float4*)(cbf + w * 256 + pq * 64 + it * 4);
                        *(float2*)(out + obase + it * 4)     = make_float2(f4.x, f4.y);
                        *(float2*)(out + obase + it * 4 + 2) = make_float2(f4.z, f4.w);
                    }
                    if (pq == 0) out[2 + gr] = (float)w;
                }
            }
        }
    }

    #pragma unroll
    for (int d = 1; d < 64; d <<= 1) lacc += __shfl_xor(lacc, d);
    if ((tid & 63) == 0) sRed[tid >> 6] = lacc;
    __syncthreads();
    if (tid == 0) {
        double s = 0.0;
        #pragma unroll
        for (int i = 0; i < 8; ++i) s += sRed[i];
        atomicAdd(wsum, s);
    }
}

__global__ void vq_fin(const double* wsum, float* out, int n) {
    if (threadIdx.x == 0 && blockIdx.x == 0) {
        double m = 0.0;
        for (int i = 0; i < n; ++i) m += wsum[i];
        m /= ((double)B_ROWS * (double)D_EMB);
        out[0] = (float)m;
        out[1] = (float)(0.25 * m);
    }
}

extern "C" void kernel_launch(void* const* d_in, const int* in_sizes, int n_in,
                              void* d_out, int out_size, void* d_ws, size_t ws_size,
                              hipStream_t stream) {
    const int*   nt  = (const int*)d_in[0];
    const float* zf  = (const float*)d_in[1];
    const float* cbf = (const float*)d_in[2];
    float*  out  = (float*)d_out;
    double* wsum = (double*)((char*)d_ws + WS_WSUM);

    hipMemsetAsync(d_ws, 0, 1024, stream);

    if (ws_size >= (size_t)WS_NEED) {
        unsigned short* cbh  = (unsigned short*)((char*)d_ws + WS_CBH);
        unsigned short* cbl  = (unsigned short*)((char*)d_ws + WS_CBL);
        float* eN    = (float*)((char*)d_ws + WS_EN);
        int*   gcnt  = (int*)((char*)d_ws + WS_GCNT);
        int*   gposD = (int*)((char*)d_ws + WS_GPOSD);
        int*   rowsp = (int*)((char*)d_ws + WS_ROWS);
        vq_prep2<<<512, 256, 0, stream>>>(cbf, nt, cbh, cbl, eN, gcnt);
        vq_binoff<<<512, 256, 0, stream>>>(nt, gcnt, gposD, rowsp);
        vq_score11<<<SGRID, TPB, 0, stream>>>(zf, cbf, cbh, cbl, eN, rowsp, gcnt,
                                              out, wsum);
        vq_fin<<<1, 64, 0, stream>>>(wsum, out, 64);
    } else {
        int* flag = (int*)((char*)d_ws + WS_FLAGS);
        vq_detect<<<1, 64, 0, stream>>>((const unsigned short*)cbf, nt, flag);
        vq_main_f32<<<256, 512, 0, stream>>>(nt, zf, cbf, out, wsum, flag);
        vq_fin<<<1, 64, 0, stream>>>(wsum, out, 1);
    }
}